// Round 1
// baseline (557.682 us; speedup 1.0000x reference)
//
#include <hip/hip_runtime.h>

#define BB 64
#define TT 1024
#define CC 2
#define NN 128

#define REP16(M) M(0)M(1)M(2)M(3)M(4)M(5)M(6)M(7)M(8)M(9)M(10)M(11)M(12)M(13)M(14)M(15)

// fp32 -> bf16 bits, round-to-nearest-even (inputs are never NaN here)
static __device__ __forceinline__ unsigned f2bf(float x) {
    const unsigned u = __float_as_uint(x);
    return (u + 0x7FFFu + ((u >> 16) & 1u)) >> 16;
}
static __device__ __forceinline__ unsigned pk2(float lo, float hi) {
    return f2bf(lo) | (f2bf(hi) << 16);
}

// D.f32 += S0.bf16[0]*S1.bf16[0] + S0.bf16[1]*S1.bf16[1]  (VOP3P, full rate)
#define DOT(acc, pp, ee) \
    asm("v_dot2_f32_bf16 %0, %1, %2, %0" : "+v"(acc) : "v"(pp), "v"(ee));

// Chunk c covers i = 8c..8c+7: 4 packed bf16 pairs of exp(trans[c][i][j]).
#define E_INIT(c) \
    unsigned ue##c##_0 = pk2(__expf(tr[(8*(c)+0)*NN + j]), __expf(tr[(8*(c)+1)*NN + j])); \
    unsigned ue##c##_1 = pk2(__expf(tr[(8*(c)+2)*NN + j]), __expf(tr[(8*(c)+3)*NN + j])); \
    unsigned ue##c##_2 = pk2(__expf(tr[(8*(c)+4)*NN + j]), __expf(tr[(8*(c)+5)*NN + j])); \
    unsigned ue##c##_3 = pk2(__expf(tr[(8*(c)+6)*NN + j]), __expf(tr[(8*(c)+7)*NN + j]));

// Opaque pin: prevents remat/sinking of the packed E registers.
#define E_PIN(c) \
    asm volatile("" : "+v"(ue##c##_0), "+v"(ue##c##_1), "+v"(ue##c##_2), "+v"(ue##c##_3));

// 8 MACs: one b128 broadcast read (4 packed p-pairs) + 4 dot2.
#define MV(c) { const uint4 q = pb[c]; \
    DOT(a0, q.x, ue##c##_0) DOT(a1, q.y, ue##c##_1) \
    DOT(a2, q.z, ue##c##_2) DOT(a3, q.w, ue##c##_3) }

// Raw workgroup barrier: producer-visibility via lgkmcnt(0) ONLY.
// __syncthreads() makes the compiler emit "s_waitcnt vmcnt(0) lgkmcnt(0)"
// before s_barrier, which drained the 2-deep emission prefetch EVERY step
// (~500 cyc of L3/HBM latency on the serial critical path). LDS ordering
// only needs lgkmcnt; global loads (vmcnt) may stay in flight across the
// barrier. Pattern proven in learn_hip m139/m201. WAR safety: every wave's
// lgkmcnt(0) at the NEXT barrier drains its ds_reads before any wave can
// re-write that buffer two iterations later.
static __device__ __forceinline__ void wg_barrier() {
    asm volatile("s_waitcnt lgkmcnt(0)" ::: "memory");
    __builtin_amdgcn_s_barrier();
    asm volatile("" ::: "memory");
}

// One workgroup (128 thr = 2 waves) per (b,c) chain; thread j owns tag j and
// the full E column as 64 packed-bf16 VGPRs. amdgpu_waves_per_eu(1,1) caps
// occupancy at 1 wave/EU so the allocator stops spilling E.
//
// Critical-path factoring: alpha_t = S_t + log(s_t) + e_t, so
//   p_{t+1} = exp(alpha_t - S_{t+1}) = s_t * exp(S_t + e_t - S_{t+1})
// The factor f = exp(S_t + e_t - S_{t+1}) uses only stale broadcast shifts
// and the prefetched emission -> __expf runs in PARALLEL with the dot2s.
// Serial chain per step: dot -> mul -> bf16 pack -> ds_write -> barrier ->
// ds_read -> dot. __logf survives only on thread 0's shift side-path
// (2 steps of slack) and in the epilogue. Exact re-association of the
// previous math; stale shift is conditioning only (exponents ~e^25).
__global__ __launch_bounds__(128, 1) __attribute__((amdgpu_waves_per_eu(1, 1)))
void crf_logz_kernel(const float* __restrict__ emissions,
                     const int* __restrict__ lengths,
                     const float* __restrict__ transitions,
                     const float* __restrict__ start_trans,
                     const float* __restrict__ end_trans,
                     float* __restrict__ out)
{
    const int bc = blockIdx.x;
    const int b  = bc >> 1;
    const int c  = bc & 1;
    const int j  = threadIdx.x;            // 0..127, owns tag j

    __shared__ __align__(16) unsigned short pbufs[2][NN];  // bf16 p, double-buffered
    __shared__ float shbuf[2];             // shift broadcast (alpha_t[0]), parity-buffered
    __shared__ float red[NN];              // final reduction scratch

    const float* tr = transitions + c * NN * NN;
    REP16(E_INIT)                          // 64 packed regs = 128 bf16 E values
    REP16(E_PIN)

    const int len  = lengths[b];           // in [T/2, T]
    const int tmax = len - 1;

    // emissions[b][t][c][*]; t-stride = CC*NN floats; coalesced per wave
    const float* emisb = emissions + ((size_t)b * TT * CC + c) * NN;

    const float alpha0 = start_trans[c * NN + j] + emisb[j];  // alpha_0[j]
    if (j == 0) shbuf[0] = alpha0;         // S_2 = alpha_0[0]; visible after barrier t=1

    // p_1 = exp(alpha_0 - S_1) with S_1 = 0 (|alpha_0| < ~12)
    unsigned pbits = f2bf(__expf(alpha0));
    float Scur = 0.f;                      // S_t for t = 1

    // 2-deep register emission pipeline (in flight across raw barriers)
    const int t1 = (1 < tmax) ? 1 : tmax, t2 = (2 < tmax) ? 2 : tmax;
    float ecur = emisb[(size_t)t1 * (CC * NN) + j];   // e_t
    float enx  = emisb[(size_t)t2 * (CC * NN) + j];   // e_{t+1}

    float s = 0.f, Sfin = 0.f, efin = ecur;

    for (int t = 1; t < len; ++t) {
        pbufs[t & 1][j] = (unsigned short)pbits;   // p_t, packed last iteration
        wg_barrier();                              // lgkm-only: vmcnt stays in flight

        // prefetch emission for t+2 (clamped); never drained by the barrier
        const int tp = (t + 2 <= tmax) ? (t + 2) : tmax;
        const float el = emisb[(size_t)tp * (CC * NN) + j];

        const float Snxt = shbuf[(t - 1) & 1];     // S_{t+1} = alpha_{t-1}[0]
        const float f = __expf(Scur + ecur - Snxt); // || with dots (no dep on s)

        const uint4* __restrict__ pb = (const uint4*)pbufs[t & 1];
        float a0 = 0.f, a1 = 0.f, a2 = 0.f, a3 = 0.f;
        REP16(MV)                          // 16 b128 broadcasts + 64 dot2
        s = (a0 + a1) + (a2 + a3);         // s_t[j]

        // S_{t+2} = alpha_t[0]; thread 0's log has 2 steps of slack
        if (j == 0) shbuf[t & 1] = Scur + __logf(s) + ecur;

        pbits = f2bf(s * f);               // p_{t+1}[j] -> bf16 (critical: 1 mul + pack)

        Sfin = Scur; efin = ecur;          // snapshot for epilogue
        Scur = Snxt; ecur = enx; enx = el;
    }

    // alpha_{len-1}[j] = S_{len-1} + log(s_{len-1}[j]) + e_{len-1}[j]
    const float alpha = (tmax == 0) ? alpha0 : (Sfin + __logf(s) + efin);

    // final logsumexp over tags
    red[j] = alpha + end_trans[c * NN + j];
    __syncthreads();
    if (j < 64) {
        const float x = red[j], y = red[j + 64];
        float m = fmaxf(x, y);
        #pragma unroll
        for (int off = 32; off > 0; off >>= 1)
            m = fmaxf(m, __shfl_xor(m, off));
        float ssum = __expf(x - m) + __expf(y - m);
        #pragma unroll
        for (int off = 32; off > 0; off >>= 1)
            ssum += __shfl_xor(ssum, off);
        if (j == 0) out[b * CC + c] = m + __logf(ssum);
    }
}

extern "C" void kernel_launch(void* const* d_in, const int* in_sizes, int n_in,
                              void* d_out, int out_size, void* d_ws, size_t ws_size,
                              hipStream_t stream) {
    const float* emissions   = (const float*)d_in[0];
    const int*   lengths     = (const int*)d_in[1];
    const float* transitions = (const float*)d_in[2];
    const float* start_t     = (const float*)d_in[3];
    const float* end_t       = (const float*)d_in[4];
    float* out = (float*)d_out;

    crf_logz_kernel<<<BB * CC, NN, 0, stream>>>(
        emissions, lengths, transitions, start_t, end_t, out);
}